// Round 1
// baseline (198.900 us; speedup 1.0000x reference)
//
#include <hip/hip_runtime.h>
#include <hip/hip_bf16.h>

#define LQ 2048
#define LKV 2048
#define DM 512
#define NH 8
#define DK 64

typedef __attribute__((ext_vector_type(8))) __bf16 bf16x8;
typedef __attribute__((ext_vector_type(4))) float f32x4;

static __device__ __forceinline__ unsigned short f2bf(float x) {
  unsigned u = __float_as_uint(x);
  return (unsigned short)((u + 0x7fffu + ((u >> 16) & 1u)) >> 16);
}

// ---------------------------------------------------------------------------
// Transpose+convert W[512][512] f32 -> Wt[512][512] bf16 (Wt[n][k] = W[k][n])
// grid (16,16,4), block 256
// ---------------------------------------------------------------------------
__global__ __launch_bounds__(256) void transpose_w(
    const float* __restrict__ Wq, const float* __restrict__ Wk,
    const float* __restrict__ Wv, const float* __restrict__ Wo,
    unsigned short* __restrict__ WtAll)
{
  const float* W = blockIdx.z == 0 ? Wq : blockIdx.z == 1 ? Wk : blockIdx.z == 2 ? Wv : Wo;
  unsigned short* Wt = WtAll + (size_t)blockIdx.z * DM * DM;
  __shared__ float tile[32][33];
  const int t = threadIdx.x;
  const int tr = t >> 3;          // 0..31
  const int tc4 = (t & 7) * 4;    // 0,4,...,28
  const int k0 = blockIdx.x * 32, n0 = blockIdx.y * 32;
  float4 v = *(const float4*)(W + (size_t)(k0 + tr) * DM + n0 + tc4);
  tile[tr][tc4 + 0] = v.x; tile[tr][tc4 + 1] = v.y;
  tile[tr][tc4 + 2] = v.z; tile[tr][tc4 + 3] = v.w;
  __syncthreads();
  ushort4 o;
  o.x = f2bf(tile[tc4 + 0][tr]);
  o.y = f2bf(tile[tc4 + 1][tr]);
  o.z = f2bf(tile[tc4 + 2][tr]);
  o.w = f2bf(tile[tc4 + 3][tr]);
  *(ushort4*)(Wt + (size_t)(n0 + tr) * DM + k0 + tc4) = o;
}

// ---------------------------------------------------------------------------
// QKV projection GEMM: A[8192][512] f32 @ Wt^T + b -> head-major bf16 [B,H,L,64]
// tile 128x128, BK=32, 4 waves (2x2 of 64x64). grid (64,4,3), block 256
// ---------------------------------------------------------------------------
__global__ __launch_bounds__(256) void gemm_qkv(
    const float* __restrict__ qin, const float* __restrict__ kin, const float* __restrict__ vin,
    const unsigned short* __restrict__ WtAll,
    const float* __restrict__ bq, const float* __restrict__ bk, const float* __restrict__ bv,
    unsigned short* __restrict__ qh, unsigned short* __restrict__ kh, unsigned short* __restrict__ vh)
{
  const int mode = blockIdx.z;
  const float* A = mode == 0 ? qin : (mode == 1 ? kin : vin);
  const unsigned short* Bt = WtAll + (size_t)mode * DM * DM;
  const float* bias = mode == 0 ? bq : (mode == 1 ? bk : bv);
  unsigned short* out = mode == 0 ? qh : (mode == 1 ? kh : vh);

  __shared__ __align__(16) unsigned short Al[128 * 40];
  __shared__ __align__(16) unsigned short Bl[128 * 40];

  const int tid = threadIdx.x;
  const int lane = tid & 63;
  const int w = tid >> 6;
  const int wr = w >> 1, wc = w & 1;
  const int l15 = lane & 15, g = lane >> 4;
  const int m0 = blockIdx.x * 128, n0 = blockIdx.y * 128;

  f32x4 acc[4][4] = {};

  for (int k0 = 0; k0 < DM; k0 += 32) {
    // stage A (f32 -> bf16), 128 rows x 32 k
#pragma unroll
    for (int i = 0; i < 4; ++i) {
      int idx = tid + i * 256;
      int row = idx >> 3, seg = idx & 7;
      float4 v = *(const float4*)(A + (size_t)(m0 + row) * DM + k0 + seg * 4);
      ushort4 pk;
      pk.x = f2bf(v.x); pk.y = f2bf(v.y); pk.z = f2bf(v.z); pk.w = f2bf(v.w);
      *(ushort4*)(&Al[row * 40 + seg * 4]) = pk;
    }
    // stage Bt (bf16), rows are n
#pragma unroll
    for (int i = 0; i < 2; ++i) {
      int idx = tid + i * 256;
      int row = idx >> 2, seg = idx & 3;
      *(int4*)(&Bl[row * 40 + seg * 8]) =
          *(const int4*)(Bt + (size_t)(n0 + row) * DM + k0 + seg * 8);
    }
    __syncthreads();
    bf16x8 af[4], bfr[4];
#pragma unroll
    for (int mi = 0; mi < 4; ++mi)
      af[mi] = *(const bf16x8*)(&Al[(wr * 64 + mi * 16 + l15) * 40 + g * 8]);
#pragma unroll
    for (int ni = 0; ni < 4; ++ni)
      bfr[ni] = *(const bf16x8*)(&Bl[(wc * 64 + ni * 16 + l15) * 40 + g * 8]);
#pragma unroll
    for (int mi = 0; mi < 4; ++mi)
#pragma unroll
      for (int ni = 0; ni < 4; ++ni)
        acc[mi][ni] = __builtin_amdgcn_mfma_f32_16x16x32_bf16(af[mi], bfr[ni], acc[mi][ni], 0, 0, 0);
    __syncthreads();
  }

#pragma unroll
  for (int mi = 0; mi < 4; ++mi) {
#pragma unroll
    for (int ni = 0; ni < 4; ++ni) {
      int n = n0 + wc * 64 + ni * 16 + l15;
      float bs = bias[n];
      int h = n >> 6, d = n & 63;
#pragma unroll
      for (int r = 0; r < 4; ++r) {
        int m = m0 + wr * 64 + mi * 16 + g * 4 + r;
        int b = m >> 11, li = m & 2047;
        float val = acc[mi][ni][r] + bs;
        out[(((size_t)(b * NH + h)) * LQ + li) * DK + d] = f2bf(val);
      }
    }
  }
}

// ---------------------------------------------------------------------------
// Output GEMM: A[8192][512] bf16 @ Wo^T + bo -> f32 [8192][512]
// ---------------------------------------------------------------------------
__global__ __launch_bounds__(256) void gemm_out(
    const unsigned short* __restrict__ A, const unsigned short* __restrict__ Bt,
    const float* __restrict__ bias, float* __restrict__ out)
{
  __shared__ __align__(16) unsigned short Al[128 * 40];
  __shared__ __align__(16) unsigned short Bl[128 * 40];
  const int tid = threadIdx.x;
  const int lane = tid & 63;
  const int w = tid >> 6;
  const int wr = w >> 1, wc = w & 1;
  const int l15 = lane & 15, g = lane >> 4;
  const int m0 = blockIdx.x * 128, n0 = blockIdx.y * 128;
  f32x4 acc[4][4] = {};

  for (int k0 = 0; k0 < DM; k0 += 32) {
#pragma unroll
    for (int i = 0; i < 2; ++i) {
      int idx = tid + i * 256;
      int row = idx >> 2, seg = idx & 3;
      *(int4*)(&Al[row * 40 + seg * 8]) =
          *(const int4*)(A + (size_t)(m0 + row) * DM + k0 + seg * 8);
      *(int4*)(&Bl[row * 40 + seg * 8]) =
          *(const int4*)(Bt + (size_t)(n0 + row) * DM + k0 + seg * 8);
    }
    __syncthreads();
    bf16x8 af[4], bfr[4];
#pragma unroll
    for (int mi = 0; mi < 4; ++mi)
      af[mi] = *(const bf16x8*)(&Al[(wr * 64 + mi * 16 + l15) * 40 + g * 8]);
#pragma unroll
    for (int ni = 0; ni < 4; ++ni)
      bfr[ni] = *(const bf16x8*)(&Bl[(wc * 64 + ni * 16 + l15) * 40 + g * 8]);
#pragma unroll
    for (int mi = 0; mi < 4; ++mi)
#pragma unroll
      for (int ni = 0; ni < 4; ++ni)
        acc[mi][ni] = __builtin_amdgcn_mfma_f32_16x16x32_bf16(af[mi], bfr[ni], acc[mi][ni], 0, 0, 0);
    __syncthreads();
  }

#pragma unroll
  for (int mi = 0; mi < 4; ++mi) {
#pragma unroll
    for (int ni = 0; ni < 4; ++ni) {
      int n = n0 + wc * 64 + ni * 16 + l15;
      float bs = bias[n];
#pragma unroll
      for (int r = 0; r < 4; ++r) {
        int m = m0 + wr * 64 + mi * 16 + g * 4 + r;
        out[(size_t)m * DM + n] = acc[mi][ni][r] + bs;
      }
    }
  }
}

// ---------------------------------------------------------------------------
// V transpose: vh[b,h,l,d] -> vt[b,h,d,l]   grid (32, 32), block 256
// ---------------------------------------------------------------------------
__global__ __launch_bounds__(256) void transpose_v(
    const unsigned short* __restrict__ vh, unsigned short* __restrict__ vt)
{
  __shared__ __align__(16) unsigned short t[64 * 72];
  const int bh = blockIdx.y, l0 = blockIdx.x * 64;
  const size_t base = (size_t)bh * LKV * DK;
  const int tid = threadIdx.x;
#pragma unroll
  for (int i = 0; i < 2; ++i) {
    int idx = tid + i * 256;
    int row = idx >> 3, seg = idx & 7;
    *(int4*)(&t[row * 72 + seg * 8]) =
        *(const int4*)(vh + base + (size_t)(l0 + row) * DK + seg * 8);
  }
  __syncthreads();
#pragma unroll
  for (int i = 0; i < 2; ++i) {
    int idx = tid + i * 256;
    int d = idx >> 3, seg = idx & 7;
    unsigned short t0 = t[(seg * 8 + 0) * 72 + d];
    unsigned short t1 = t[(seg * 8 + 1) * 72 + d];
    unsigned short t2 = t[(seg * 8 + 2) * 72 + d];
    unsigned short t3 = t[(seg * 8 + 3) * 72 + d];
    unsigned short t4 = t[(seg * 8 + 4) * 72 + d];
    unsigned short t5 = t[(seg * 8 + 5) * 72 + d];
    unsigned short t6 = t[(seg * 8 + 6) * 72 + d];
    unsigned short t7 = t[(seg * 8 + 7) * 72 + d];
    int4 o;
    o.x = (int)((unsigned)t0 | ((unsigned)t1 << 16));
    o.y = (int)((unsigned)t2 | ((unsigned)t3 << 16));
    o.z = (int)((unsigned)t4 | ((unsigned)t5 << 16));
    o.w = (int)((unsigned)t6 | ((unsigned)t7 << 16));
    *(int4*)(vt + base + (size_t)d * LKV + l0 + seg * 8) = o;
  }
}

// ---------------------------------------------------------------------------
// Flash attention with folded log-weight bias.
// grid (LQ/64, B*H), block 256 (4 waves x 16 q-rows). KV tile = 64.
// softmax(s/8 + ln w) streamed; P through per-wave LDS; PV via MFMA.
// ---------------------------------------------------------------------------
__global__ __launch_bounds__(256) void attn_fwd(
    const unsigned short* __restrict__ qh, const unsigned short* __restrict__ kh,
    const unsigned short* __restrict__ vt, const float* __restrict__ wts,
    unsigned short* __restrict__ ao)
{
  const int bh = blockIdx.y;
  const int b = bh >> 3, h = bh & 7;
  const int qb = blockIdx.x;
  const int tid = threadIdx.x, lane = tid & 63, w = tid >> 6;
  const int l15 = lane & 15, g = lane >> 4;

  __shared__ __align__(16) unsigned short Kl[64 * 72];
  __shared__ __align__(16) unsigned short Vl[64 * 72];
  __shared__ __align__(16) unsigned short Pl[64 * 72];
  __shared__ float lwl[64];

  const size_t basebh = (size_t)bh * LKV * DK;

  const int qrow = qb * 64 + w * 16 + l15;
  bf16x8 qf0 = *(const bf16x8*)(qh + basebh + (size_t)qrow * DK + g * 8);
  bf16x8 qf1 = *(const bf16x8*)(qh + basebh + (size_t)qrow * DK + 32 + g * 8);

  float mrow[4], lrow[4];
#pragma unroll
  for (int r = 0; r < 4; ++r) { mrow[r] = -3.0e38f; lrow[r] = 0.f; }
  f32x4 accO[4] = {};

  for (int kv0 = 0; kv0 < LKV; kv0 += 64) {
#pragma unroll
    for (int i = 0; i < 2; ++i) {
      int idx = tid + i * 256;
      int row = idx >> 3, seg = idx & 7;
      *(int4*)(&Kl[row * 72 + seg * 8]) =
          *(const int4*)(kh + basebh + (size_t)(kv0 + row) * DK + seg * 8);
      *(int4*)(&Vl[row * 72 + seg * 8]) =
          *(const int4*)(vt + basebh + (size_t)row * LKV + kv0 + seg * 8);
    }
    if (tid < 64) lwl[tid] = __logf(wts[b * LKV + kv0 + tid]);
    __syncthreads();

    // S = Q K^T  (16 q-rows x 64 kv), C layout: row=g*4+r, col=l15
    f32x4 S[4];
#pragma unroll
    for (int f = 0; f < 4; ++f) {
      bf16x8 ka = *(const bf16x8*)(&Kl[(f * 16 + l15) * 72 + g * 8]);
      bf16x8 kb = *(const bf16x8*)(&Kl[(f * 16 + l15) * 72 + 32 + g * 8]);
      f32x4 s = {};
      s = __builtin_amdgcn_mfma_f32_16x16x32_bf16(qf0, ka, s, 0, 0, 0);
      s = __builtin_amdgcn_mfma_f32_16x16x32_bf16(qf1, kb, s, 0, 0, 0);
      S[f] = s;
    }

    float sval[4][4];
#pragma unroll
    for (int f = 0; f < 4; ++f) {
      float lw = lwl[f * 16 + l15];
#pragma unroll
      for (int r = 0; r < 4; ++r) sval[f][r] = S[f][r] * 0.125f + lw;
    }

    float p[4][4];
#pragma unroll
    for (int r = 0; r < 4; ++r) {
      float mt = fmaxf(fmaxf(sval[0][r], sval[1][r]), fmaxf(sval[2][r], sval[3][r]));
      mt = fmaxf(mt, __shfl_xor(mt, 1));
      mt = fmaxf(mt, __shfl_xor(mt, 2));
      mt = fmaxf(mt, __shfl_xor(mt, 4));
      mt = fmaxf(mt, __shfl_xor(mt, 8));
      float mn = fmaxf(mrow[r], mt);
      float alpha = exp2f((mrow[r] - mn) * 1.44269504f);
      mrow[r] = mn;
      float rs = 0.f;
#pragma unroll
      for (int f = 0; f < 4; ++f) {
        float pv = exp2f((sval[f][r] - mn) * 1.44269504f);
        p[f][r] = pv; rs += pv;
      }
      rs += __shfl_xor(rs, 1);
      rs += __shfl_xor(rs, 2);
      rs += __shfl_xor(rs, 4);
      rs += __shfl_xor(rs, 8);
      lrow[r] = lrow[r] * alpha + rs;
#pragma unroll
      for (int d = 0; d < 4; ++d) accO[d][r] *= alpha;
    }

    // P -> per-wave LDS region (rows w*16 .. w*16+15)
#pragma unroll
    for (int f = 0; f < 4; ++f)
#pragma unroll
      for (int r = 0; r < 4; ++r)
        Pl[(w * 16 + g * 4 + r) * 72 + f * 16 + l15] = f2bf(p[f][r]);

    // O += P V
#pragma unroll
    for (int ks = 0; ks < 2; ++ks) {
      bf16x8 pa = *(const bf16x8*)(&Pl[(w * 16 + l15) * 72 + ks * 32 + g * 8]);
#pragma unroll
      for (int d = 0; d < 4; ++d) {
        bf16x8 vb = *(const bf16x8*)(&Vl[(d * 16 + l15) * 72 + ks * 32 + g * 8]);
        accO[d] = __builtin_amdgcn_mfma_f32_16x16x32_bf16(pa, vb, accO[d], 0, 0, 0);
      }
    }
    __syncthreads();
  }

#pragma unroll
  for (int r = 0; r < 4; ++r) {
    float inv = 1.0f / lrow[r];
    int qg = qb * 64 + w * 16 + g * 4 + r;
#pragma unroll
    for (int d = 0; d < 4; ++d)
      ao[((size_t)(b * LQ + qg)) * DM + h * DK + d * 16 + l15] = f2bf(accO[d][r] * inv);
  }
}

// ---------------------------------------------------------------------------
extern "C" void kernel_launch(void* const* d_in, const int* in_sizes, int n_in,
                              void* d_out, int out_size, void* d_ws, size_t ws_size,
                              hipStream_t stream)
{
  const float* q  = (const float*)d_in[0];
  const float* k  = (const float*)d_in[1];
  const float* v  = (const float*)d_in[2];
  const float* wt = (const float*)d_in[3];
  const float* Wq = (const float*)d_in[4];
  const float* bq = (const float*)d_in[5];
  const float* Wk = (const float*)d_in[6];
  const float* bk = (const float*)d_in[7];
  const float* Wv = (const float*)d_in[8];
  const float* bv = (const float*)d_in[9];
  const float* Wo = (const float*)d_in[10];
  const float* bo = (const float*)d_in[11];

  char* ws = (char*)d_ws;
  unsigned short* qh = (unsigned short*)(ws + 0);           //  8 MiB  [B,H,L,64]
  unsigned short* kh = (unsigned short*)(ws + 8388608);     //  8 MiB  [B,H,L,64]
  unsigned short* vtr= (unsigned short*)(ws + 16777216);    //  8 MiB  [B,H,64,L]
  unsigned short* ao = (unsigned short*)(ws + 25165824);    //  8 MiB  [B,L,512]
  unsigned short* Wt = (unsigned short*)(ws + 33554432);    //  2 MiB  4x[512][512]
  unsigned short* vh = (unsigned short*)(ws + 35651584);    //  8 MiB  [B,H,L,64]

  transpose_w<<<dim3(16, 16, 4), 256, 0, stream>>>(Wq, Wk, Wv, Wo, Wt);
  gemm_qkv<<<dim3(64, 4, 3), 256, 0, stream>>>(q, k, v, Wt, bq, bk, bv, qh, kh, vh);
  transpose_v<<<dim3(32, 32), 256, 0, stream>>>(vh, vtr);
  attn_fwd<<<dim3(32, 32), 256, 0, stream>>>(qh, kh, vtr, wt, ao);
  gemm_out<<<dim3(64, 4), 256, 0, stream>>>(ao, Wt + 3 * (size_t)DM * DM, bo, (float*)d_out);
}

// Round 2
// 141.440 us; speedup vs baseline: 1.4063x; 1.4063x over previous
//
#include <hip/hip_runtime.h>
#include <hip/hip_bf16.h>

#define LQ 2048
#define LKV 2048
#define DM 512
#define NH 8
#define DK 64

typedef __attribute__((ext_vector_type(8))) __bf16 bf16x8;
typedef __attribute__((ext_vector_type(4))) float f32x4;
typedef __attribute__((ext_vector_type(16))) float f32x16;

static __device__ __forceinline__ unsigned short f2bf(float x) {
  unsigned u = __float_as_uint(x);
  return (unsigned short)((u + 0x7fffu + ((u >> 16) & 1u)) >> 16);
}
static __device__ __forceinline__ float bf2f(unsigned short u) {
  return __uint_as_float(((unsigned)u) << 16);
}

// ---------------------------------------------------------------------------
// Transpose+convert W[512][512] f32 -> Wt[512][512] bf16 (Wt[n][k] = W[k][n])
// ---------------------------------------------------------------------------
__global__ __launch_bounds__(256) void transpose_w(
    const float* __restrict__ Wq, const float* __restrict__ Wk,
    const float* __restrict__ Wv, const float* __restrict__ Wo,
    unsigned short* __restrict__ WtAll)
{
  const float* W = blockIdx.z == 0 ? Wq : blockIdx.z == 1 ? Wk : blockIdx.z == 2 ? Wv : Wo;
  unsigned short* Wt = WtAll + (size_t)blockIdx.z * DM * DM;
  __shared__ float tile[32][33];
  const int t = threadIdx.x;
  const int tr = t >> 3;
  const int tc4 = (t & 7) * 4;
  const int k0 = blockIdx.x * 32, n0 = blockIdx.y * 32;
  float4 v = *(const float4*)(W + (size_t)(k0 + tr) * DM + n0 + tc4);
  tile[tr][tc4 + 0] = v.x; tile[tr][tc4 + 1] = v.y;
  tile[tr][tc4 + 2] = v.z; tile[tr][tc4 + 3] = v.w;
  __syncthreads();
  ushort4 o;
  o.x = f2bf(tile[tc4 + 0][tr]);
  o.y = f2bf(tile[tc4 + 1][tr]);
  o.z = f2bf(tile[tc4 + 2][tr]);
  o.w = f2bf(tile[tc4 + 3][tr]);
  *(ushort4*)(Wt + (size_t)(n0 + tr) * DM + k0 + tc4) = o;
}

// ---------------------------------------------------------------------------
// QKV projection GEMM -> head-major bf16 [B,H,L,64]; q scaled by log2e/8
// ---------------------------------------------------------------------------
__global__ __launch_bounds__(256) void gemm_qkv(
    const float* __restrict__ qin, const float* __restrict__ kin, const float* __restrict__ vin,
    const unsigned short* __restrict__ WtAll,
    const float* __restrict__ bq, const float* __restrict__ bk, const float* __restrict__ bv,
    unsigned short* __restrict__ qh, unsigned short* __restrict__ kh, unsigned short* __restrict__ vh)
{
  const int mode = blockIdx.z;
  const float* A = mode == 0 ? qin : (mode == 1 ? kin : vin);
  const unsigned short* Bt = WtAll + (size_t)mode * DM * DM;
  const float* bias = mode == 0 ? bq : (mode == 1 ? bk : bv);
  unsigned short* out = mode == 0 ? qh : (mode == 1 ? kh : vh);
  const float scale = (mode == 0) ? 0.18033688011112042f : 1.0f; // log2(e)/8

  __shared__ __align__(16) unsigned short Al[128 * 40];
  __shared__ __align__(16) unsigned short Bl[128 * 40];

  const int tid = threadIdx.x;
  const int lane = tid & 63;
  const int w = tid >> 6;
  const int wr = w >> 1, wc = w & 1;
  const int l15 = lane & 15, g = lane >> 4;
  const int m0 = blockIdx.x * 128, n0 = blockIdx.y * 128;

  f32x4 acc[4][4] = {};

  for (int k0 = 0; k0 < DM; k0 += 32) {
#pragma unroll
    for (int i = 0; i < 4; ++i) {
      int idx = tid + i * 256;
      int row = idx >> 3, seg = idx & 7;
      float4 v = *(const float4*)(A + (size_t)(m0 + row) * DM + k0 + seg * 4);
      ushort4 pk;
      pk.x = f2bf(v.x); pk.y = f2bf(v.y); pk.z = f2bf(v.z); pk.w = f2bf(v.w);
      *(ushort4*)(&Al[row * 40 + seg * 4]) = pk;
    }
#pragma unroll
    for (int i = 0; i < 2; ++i) {
      int idx = tid + i * 256;
      int row = idx >> 2, seg = idx & 3;
      *(int4*)(&Bl[row * 40 + seg * 8]) =
          *(const int4*)(Bt + (size_t)(n0 + row) * DM + k0 + seg * 8);
    }
    __syncthreads();
    bf16x8 af[4], bfr[4];
#pragma unroll
    for (int mi = 0; mi < 4; ++mi)
      af[mi] = *(const bf16x8*)(&Al[(wr * 64 + mi * 16 + l15) * 40 + g * 8]);
#pragma unroll
    for (int ni = 0; ni < 4; ++ni)
      bfr[ni] = *(const bf16x8*)(&Bl[(wc * 64 + ni * 16 + l15) * 40 + g * 8]);
#pragma unroll
    for (int mi = 0; mi < 4; ++mi)
#pragma unroll
      for (int ni = 0; ni < 4; ++ni)
        acc[mi][ni] = __builtin_amdgcn_mfma_f32_16x16x32_bf16(af[mi], bfr[ni], acc[mi][ni], 0, 0, 0);
    __syncthreads();
  }

#pragma unroll
  for (int mi = 0; mi < 4; ++mi) {
#pragma unroll
    for (int ni = 0; ni < 4; ++ni) {
      int n = n0 + wc * 64 + ni * 16 + l15;
      float bs = bias[n];
      int h = n >> 6, d = n & 63;
#pragma unroll
      for (int r = 0; r < 4; ++r) {
        int m = m0 + wr * 64 + mi * 16 + g * 4 + r;
        int b = m >> 11, li = m & 2047;
        float val = (acc[mi][ni][r] + bs) * scale;
        out[(((size_t)(b * NH + h)) * LQ + li) * DK + d] = f2bf(val);
      }
    }
  }
}

// ---------------------------------------------------------------------------
// Output GEMM: A[8192][512] bf16 @ Wo^T + bo -> f32
// ---------------------------------------------------------------------------
__global__ __launch_bounds__(256) void gemm_out(
    const unsigned short* __restrict__ A, const unsigned short* __restrict__ Bt,
    const float* __restrict__ bias, float* __restrict__ out)
{
  __shared__ __align__(16) unsigned short Al[128 * 40];
  __shared__ __align__(16) unsigned short Bl[128 * 40];
  const int tid = threadIdx.x;
  const int lane = tid & 63;
  const int w = tid >> 6;
  const int wr = w >> 1, wc = w & 1;
  const int l15 = lane & 15, g = lane >> 4;
  const int m0 = blockIdx.x * 128, n0 = blockIdx.y * 128;
  f32x4 acc[4][4] = {};

  for (int k0 = 0; k0 < DM; k0 += 32) {
#pragma unroll
    for (int i = 0; i < 2; ++i) {
      int idx = tid + i * 256;
      int row = idx >> 2, seg = idx & 3;
      *(int4*)(&Al[row * 40 + seg * 8]) =
          *(const int4*)(A + (size_t)(m0 + row) * DM + k0 + seg * 8);
      *(int4*)(&Bl[row * 40 + seg * 8]) =
          *(const int4*)(Bt + (size_t)(n0 + row) * DM + k0 + seg * 8);
    }
    __syncthreads();
    bf16x8 af[4], bfr[4];
#pragma unroll
    for (int mi = 0; mi < 4; ++mi)
      af[mi] = *(const bf16x8*)(&Al[(wr * 64 + mi * 16 + l15) * 40 + g * 8]);
#pragma unroll
    for (int ni = 0; ni < 4; ++ni)
      bfr[ni] = *(const bf16x8*)(&Bl[(wc * 64 + ni * 16 + l15) * 40 + g * 8]);
#pragma unroll
    for (int mi = 0; mi < 4; ++mi)
#pragma unroll
      for (int ni = 0; ni < 4; ++ni)
        acc[mi][ni] = __builtin_amdgcn_mfma_f32_16x16x32_bf16(af[mi], bfr[ni], acc[mi][ni], 0, 0, 0);
    __syncthreads();
  }

#pragma unroll
  for (int mi = 0; mi < 4; ++mi) {
#pragma unroll
    for (int ni = 0; ni < 4; ++ni) {
      int n = n0 + wc * 64 + ni * 16 + l15;
      float bs = bias[n];
#pragma unroll
      for (int r = 0; r < 4; ++r) {
        int m = m0 + wr * 64 + mi * 16 + g * 4 + r;
        out[(size_t)m * DM + n] = acc[mi][ni][r] + bs;
      }
    }
  }
}

// ---------------------------------------------------------------------------
// V transpose with weight fold: vh[b,h,l,d] -> vt[b,h,d,l] = w[l]*v
// ---------------------------------------------------------------------------
__global__ __launch_bounds__(256) void transpose_v(
    const unsigned short* __restrict__ vh, const float* __restrict__ wts,
    unsigned short* __restrict__ vt)
{
  __shared__ __align__(16) unsigned short t[64 * 72];
  const int bh = blockIdx.y, l0 = blockIdx.x * 64;
  const int b = bh >> 3;
  const size_t base = (size_t)bh * LKV * DK;
  const int tid = threadIdx.x;
#pragma unroll
  for (int i = 0; i < 2; ++i) {
    int idx = tid + i * 256;
    int row = idx >> 3, seg = idx & 7;
    *(int4*)(&t[row * 72 + seg * 8]) =
        *(const int4*)(vh + base + (size_t)(l0 + row) * DK + seg * 8);
  }
  __syncthreads();
#pragma unroll
  for (int i = 0; i < 2; ++i) {
    int idx = tid + i * 256;
    int d = idx >> 3, seg = idx & 7;
    int kvg = l0 + seg * 8;
    float4 wa = *(const float4*)(wts + b * LKV + kvg);
    float4 wb = *(const float4*)(wts + b * LKV + kvg + 4);
    unsigned short r0 = f2bf(wa.x * bf2f(t[(seg * 8 + 0) * 72 + d]));
    unsigned short r1 = f2bf(wa.y * bf2f(t[(seg * 8 + 1) * 72 + d]));
    unsigned short r2 = f2bf(wa.z * bf2f(t[(seg * 8 + 2) * 72 + d]));
    unsigned short r3 = f2bf(wa.w * bf2f(t[(seg * 8 + 3) * 72 + d]));
    unsigned short r4 = f2bf(wb.x * bf2f(t[(seg * 8 + 4) * 72 + d]));
    unsigned short r5 = f2bf(wb.y * bf2f(t[(seg * 8 + 5) * 72 + d]));
    unsigned short r6 = f2bf(wb.z * bf2f(t[(seg * 8 + 6) * 72 + d]));
    unsigned short r7 = f2bf(wb.w * bf2f(t[(seg * 8 + 7) * 72 + d]));
    int4 o;
    o.x = (int)((unsigned)r0 | ((unsigned)r1 << 16));
    o.y = (int)((unsigned)r2 | ((unsigned)r3 << 16));
    o.z = (int)((unsigned)r4 | ((unsigned)r5 << 16));
    o.w = (int)((unsigned)r6 | ((unsigned)r7 << 16));
    *(int4*)(vt + base + (size_t)d * LKV + l0 + seg * 8) = o;
  }
}

// ---------------------------------------------------------------------------
// Flash attention, swapped-QK 32x32 MFMA, no-max softmax, w folded into V.
// grid 512 (XCD-grouped), block 256 = 4 waves x 32 q-rows. KV tile = 64.
//   S^T = mfma(K, Q)   -> lane holds kv-column for q = lane&31
//   u = exp2(S), pack bf16, shfl_xor(32) exchange -> PV A-frag in registers
//   O += P (w*V) via mfma; denom += P w via w-row mfma fragment
// K/V staged via global_load_lds with XOR-swizzled source (linear LDS dest).
// ---------------------------------------------------------------------------
__global__ __launch_bounds__(256) void attn_fwd(
    const unsigned short* __restrict__ qh, const unsigned short* __restrict__ kh,
    const unsigned short* __restrict__ vt, const float* __restrict__ wts,
    unsigned short* __restrict__ ao)
{
  // XCD-grouped mapping: all 16 q-blocks of one bh on one XCD (L2 locality)
  const int bid = blockIdx.x;
  const int xcd = bid & 7, wi = bid >> 3;
  const int bh = xcd * 4 + (wi >> 4);
  const int qb = wi & 15;
  const int b = bh >> 3, h = bh & 7;
  const int tid = threadIdx.x, lane = tid & 63, w = tid >> 6;
  const int l31 = lane & 31, hi = lane >> 5;

  __shared__ __align__(16) unsigned short Kl[64 * 64];
  __shared__ __align__(16) unsigned short Vl[64 * 64];
  __shared__ __align__(16) unsigned short wl[64];

  const size_t basebh = (size_t)bh * LKV * DK;

  // Q B-fragments (hoisted): q = qb*128 + w*32 + l31, k = cq*16 + hi*8 + j
  bf16x8 qf[4];
  {
    const unsigned short* qp = qh + basebh + (size_t)(qb * 128 + w * 32 + l31) * DK + hi * 8;
#pragma unroll
    for (int cq = 0; cq < 4; ++cq) qf[cq] = *(const bf16x8*)(qp + cq * 16);
  }

  f32x16 accO0 = {}, accO1 = {}, accL = {};

  for (int kv0 = 0; kv0 < LKV; kv0 += 64) {
    // ---- stage K,V (16 KB) via global_load_lds, swizzled source ----
#pragma unroll
    for (int i = 0; i < 2; ++i) {
      int q8 = w * 2 + i;                 // 8-row group, wave-uniform
      int row = q8 * 8 + (lane >> 3);     // tile row 0..63
      int slot = (lane & 7) ^ (row & 7);  // swizzled 16B slot
      const unsigned short* gK = kh + basebh + (size_t)(kv0 + row) * DK + slot * 8;
      const unsigned short* gV = vt + basebh + (size_t)row * LKV + kv0 + slot * 8;
      __builtin_amdgcn_global_load_lds(
          (const __attribute__((address_space(1))) unsigned*)gK,
          (__attribute__((address_space(3))) unsigned*)((char*)Kl + q8 * 1024), 16, 0, 0);
      __builtin_amdgcn_global_load_lds(
          (const __attribute__((address_space(1))) unsigned*)gV,
          (__attribute__((address_space(3))) unsigned*)((char*)Vl + q8 * 1024), 16, 0, 0);
    }
    if (tid < 16) {
      float4 wv = *(const float4*)(wts + b * LKV + kv0 + tid * 4);
      ushort4 o;
      o.x = f2bf(wv.x); o.y = f2bf(wv.y); o.z = f2bf(wv.z); o.w = f2bf(wv.w);
      *(ushort4*)(&wl[tid * 4]) = o;
    }
    __syncthreads();

    // ---- S^T = K·Q^T: lane holds q=l31, kv = pat(reg)+4*hi (+32*half) ----
    f32x16 S[2];
#pragma unroll
    for (int half = 0; half < 2; ++half) {
      f32x16 s = {};
#pragma unroll
      for (int cq = 0; cq < 4; ++cq) {
        int row = half * 32 + l31;
        bf16x8 kf = *(const bf16x8*)((const char*)Kl + row * 128 + (((cq * 2 + hi) ^ (row & 7)) * 16));
        s = __builtin_amdgcn_mfma_f32_32x32x16_bf16(kf, qf[cq], s, 0, 0, 0);
      }
      S[half] = s;
    }

    // ---- u = exp2(S) (scale pre-folded into qh), pack bf16 pairs ----
    unsigned D[16];
#pragma unroll
    for (int half = 0; half < 2; ++half) {
#pragma unroll
      for (int r2 = 0; r2 < 8; ++r2) {
        float lo = exp2f(S[half][2 * r2]);
        float hv = exp2f(S[half][2 * r2 + 1]);
        __bf16 bl = (__bf16)lo, bh2 = (__bf16)hv;
        unsigned short ul = __builtin_bit_cast(unsigned short, bl);
        unsigned short uh = __builtin_bit_cast(unsigned short, bh2);
        D[half * 8 + r2] = (unsigned)ul | ((unsigned)uh << 16);
      }
    }

    // ---- exchange to PV A-frag + MFMA PV and denominator ----
#pragma unroll
    for (int c = 0; c < 4; ++c) {
      int base = 4 * (c & 1) + 8 * (c >> 1);
      unsigned s0 = hi ? D[base] : D[base + 2];
      unsigned s1 = hi ? D[base + 1] : D[base + 3];
      unsigned X0 = (unsigned)__shfl_xor((int)s0, 32);
      unsigned X1 = (unsigned)__shfl_xor((int)s1, 32);
      union { unsigned u[4]; bf16x8 v; } pa;
      pa.u[0] = hi ? X0 : D[base];
      pa.u[1] = hi ? X1 : D[base + 1];
      pa.u[2] = hi ? D[base + 2] : X0;
      pa.u[3] = hi ? D[base + 3] : X1;

      int r0 = l31, r1 = 32 + l31;
      bf16x8 vb0 = *(const bf16x8*)((const char*)Vl + r0 * 128 + (((c * 2 + hi) ^ (r0 & 7)) * 16));
      bf16x8 vb1 = *(const bf16x8*)((const char*)Vl + r1 * 128 + (((c * 2 + hi) ^ (r1 & 7)) * 16));
      bf16x8 wv8 = *(const bf16x8*)((const char*)wl + (c * 2 + hi) * 16);
      bf16x8 z = {};
      bf16x8 wb = (l31 == 0) ? wv8 : z;

      accO0 = __builtin_amdgcn_mfma_f32_32x32x16_bf16(pa.v, vb0, accO0, 0, 0, 0);
      accO1 = __builtin_amdgcn_mfma_f32_32x32x16_bf16(pa.v, vb1, accO1, 0, 0, 0);
      accL  = __builtin_amdgcn_mfma_f32_32x32x16_bf16(pa.v, wb,  accL,  0, 0, 0);
    }
    __syncthreads();
  }

  // ---- normalize + store ----
  float Lq[16];
#pragma unroll
  for (int r = 0; r < 16; ++r)
    Lq[r] = 1.0f / __shfl(accL[r], lane & 32);

  const int qbase = qb * 128 + w * 32;
#pragma unroll
  for (int r = 0; r < 16; ++r) {
    int q = (r & 3) + 8 * (r >> 2) + 4 * hi;
    size_t o = ((size_t)(b * LQ + qbase + q)) * DM + h * DK;
    ao[o + l31]      = f2bf(accO0[r] * Lq[r]);
    ao[o + 32 + l31] = f2bf(accO1[r] * Lq[r]);
  }
}

// ---------------------------------------------------------------------------
extern "C" void kernel_launch(void* const* d_in, const int* in_sizes, int n_in,
                              void* d_out, int out_size, void* d_ws, size_t ws_size,
                              hipStream_t stream)
{
  const float* q  = (const float*)d_in[0];
  const float* k  = (const float*)d_in[1];
  const float* v  = (const float*)d_in[2];
  const float* wt = (const float*)d_in[3];
  const float* Wq = (const float*)d_in[4];
  const float* bq = (const float*)d_in[5];
  const float* Wk = (const float*)d_in[6];
  const float* bk = (const float*)d_in[7];
  const float* Wv = (const float*)d_in[8];
  const float* bv = (const float*)d_in[9];
  const float* Wo = (const float*)d_in[10];
  const float* bo = (const float*)d_in[11];

  char* ws = (char*)d_ws;
  unsigned short* qh = (unsigned short*)(ws + 0);           //  8 MiB  [B,H,L,64] (scaled)
  unsigned short* kh = (unsigned short*)(ws + 8388608);     //  8 MiB  [B,H,L,64]
  unsigned short* vtr= (unsigned short*)(ws + 16777216);    //  8 MiB  [B,H,64,L] (w-scaled)
  unsigned short* ao = (unsigned short*)(ws + 25165824);    //  8 MiB  [B,L,512]
  unsigned short* Wt = (unsigned short*)(ws + 33554432);    //  2 MiB  4x[512][512]
  unsigned short* vh = (unsigned short*)(ws + 35651584);    //  8 MiB  [B,H,L,64]

  transpose_w<<<dim3(16, 16, 4), 256, 0, stream>>>(Wq, Wk, Wv, Wo, Wt);
  gemm_qkv<<<dim3(64, 4, 3), 256, 0, stream>>>(q, k, v, Wt, bq, bk, bv, qh, kh, vh);
  transpose_v<<<dim3(32, 32), 256, 0, stream>>>(vh, wt, vtr);
  attn_fwd<<<512, 256, 0, stream>>>(qh, kh, vtr, wt, ao);
  gemm_out<<<dim3(64, 4), 256, 0, stream>>>(ao, Wt + 3 * (size_t)DM * DM, bo, (float*)d_out);
}